// Round 15
// baseline (242.113 us; speedup 1.0000x reference)
//
#include <hip/hip_runtime.h>
#include <hip/hip_bf16.h>
#include <hip/hip_fp8.h>

#define EMBED 128
#define TSTEPS 128
#define NBATCH 32
#define SCANB 16              // scan blocks: 2 batch chains per block (ILP pairing)
#define VDIM 50257
#define VPAD 50304            // 786 groups * 64 cols
#define MROWS 4096            // NBATCH * TSTEPS
#define NGROUPS 786           // VPAD / 64
#define GRIDX 128             // B-sweep split: 786 = 128*6 + 18
#define GRIDY 16              // 256-row M slices
#define MAXGRP 7              // max groups per x-block
#define CONV_N4 ((VDIM * EMBED) / 4)          // 1608224 float4 elements
#define CONV_BLOCKS ((CONV_N4 + 255) / 256)   // 6283

static constexpr float LOG2E = 1.4426950408889634f;
static constexpr float LN2   = 0.6931471805599453f;

__device__ __forceinline__ float fast_exp2(float x) {
#if __has_builtin(__builtin_amdgcn_exp2f)
    return __builtin_amdgcn_exp2f(x);
#else
    return exp2f(x);
#endif
}
__device__ __forceinline__ float fast_log2(float x) {
#if __has_builtin(__builtin_amdgcn_logf)
    return __builtin_amdgcn_logf(x);
#else
    return log2f(x);
#endif
}
__device__ __forceinline__ float fast_rcp(float x) {
#if __has_builtin(__builtin_amdgcn_rcpf)
    return __builtin_amdgcn_rcpf(x);
#else
    return 1.0f / x;
#endif
}
// Branch-free tanh with Newton-refined reciprocal (R12-verified: absmax
// 0.1875, avoids libm's divergent poly/exp paths in the scan).
__device__ __forceinline__ float fast_tanh_nr(float x) {
    x = fminf(20.0f, fmaxf(-20.0f, x));
    float t = fast_exp2((2.0f * LOG2E) * x);    // e^{2x}
    float u = t + 1.0f;
    float r = fast_rcp(u);
    r = r * fmaf(-u, r, 2.0f);                  // Newton: error ~ulp^2
    return (t - 1.0f) * r;
}
__device__ __forceinline__ unsigned short f2bf_raw(float f) {
    __hip_bfloat16 h = __float2bfloat16(f);
    union { __hip_bfloat16 b; unsigned short u; } cvt;
    cvt.b = h;
    return cvt.u;
}
__device__ __forceinline__ float bf_raw2f(unsigned short u) {
    union { unsigned int u; float f; } cvt;
    cvt.u = ((unsigned int)u) << 16;
    return cvt.f;
}
// pack 2 floats -> 2 fp8 e4m3 bytes into the selected half of `old`.
// (word-select must be an ICE -> template parameter; R13 lesson)
template <bool HI>
__device__ __forceinline__ int pk_fp8(float a, float b, int old) {
#if __has_builtin(__builtin_amdgcn_cvt_pk_fp8_f32)
    return __builtin_amdgcn_cvt_pk_fp8_f32(a, b, old, HI);
#else
    __hip_fp8_e4m3 x(a), y(b);
    int v = (int)(unsigned char)x.__x | ((int)(unsigned char)y.__x << 8);
    return HI ? ((old & 0xffff) | (v << 16)) : ((old & ~0xffff) | v);
#endif
}

// ---------------------------------------------------------------------------
// K0 (fused setup): blocks [0,SCANB) = scan, TWO batch chains per block
// (round-15: R11 counters showed the scan step is ~75% latency stall at 3%
// VALU — two independent recurrence chains per block interleave so one
// chain's issue fills the other's stalls); blocks [SCANB, SCANB+CONV_BLOCKS)
// convert Wv fp32 -> fp8 e4m3 (+ zero pad rows), build bvs, zero S.
//
// Scan numerics are BIT-EXACT vs R12/R14 (absmax 0.1875): each thread
// computes its element's two half-dots in the R11-verified op order
// (accA float4-chain over k[0,64), accB over k[64,128), ((zc+vA)+vB)+bte),
// which R11 measured trajectory-identical to the shfl form; fast_tanh_nr
// unchanged.  The recurrence amplifies ~1e-6/step perturbations to ~0.2
// absmax (round-4) — do not alter the op order.
// NOTE (round-9): no cross-block producer/consumer sync — device-scope
// fences force L2 writeback/invalidate (5.6x regression).
// ---------------------------------------------------------------------------
__global__ __launch_bounds__(256) void setup_kernel(const int* __restrict__ zi,
                                                    const float* __restrict__ latent,
                                                    const float* __restrict__ Wt,
                                                    const float* __restrict__ bt,
                                                    const float* __restrict__ Wv,
                                                    const float* __restrict__ bv,
                                                    unsigned short* __restrict__ zsb,
                                                    unsigned char* __restrict__ zsa8,
                                                    unsigned char* __restrict__ wv8,
                                                    float* __restrict__ bvs,
                                                    float* __restrict__ S) {
    if (blockIdx.x >= SCANB) {
        const int cb = blockIdx.x - SCANB;
        if (cb == 0) {                      // zero the S accumulator
#pragma unroll
            for (int i = 0; i < MROWS / 256; i++)
                S[i * 256 + threadIdx.x] = 0.f;
        }
        if (cb == 1) {                      // zero fp8 pad rows of wv8
            const int base  = VDIM * EMBED / 4;          // first pad uint
            const int npad  = (VPAD - VDIM) * EMBED / 4; // 1504 uints
            for (int i = threadIdx.x; i < npad; i += 256)
                reinterpret_cast<unsigned int*>(wv8)[base + i] = 0u;
        }
        const int idx = cb * 256 + threadIdx.x;
        if (idx < VPAD)                     // prescaled, padded bias
            bvs[idx] = (idx < VDIM) ? bv[idx] * LOG2E : -1e30f;
        if (idx < CONV_N4) {
            float4 v = reinterpret_cast<const float4*>(Wv)[idx];
            int p = pk_fp8<false>(v.x, v.y, 0);
            p = pk_fp8<true>(v.z, v.w, p);
            reinterpret_cast<unsigned int*>(wv8)[idx] = (unsigned int)p;
        }
        return;
    }

    // ---- scan path: 2 batch chains per block; thread = (j = tid>>7, e) ----
    __shared__ float zbuf[2][2][EMBED];                 // [chain][pingpong][e]
    __shared__ unsigned short zstash[2][TSTEPS * EMBED];// 2 x 32 KB bf16 stash
    const int j = threadIdx.x >> 7;     // chain within block
    const int e = threadIdx.x & 127;    // output element
    const int b = blockIdx.x * 2 + j;   // batch index

    // cache the FULL Wt row e in registers (128 VGPRs)
    float4 wrowA[16], wrowB[16];
    const float4* wt4 = reinterpret_cast<const float4*>(Wt + e * EMBED);
#pragma unroll
    for (int i = 0; i < 16; i++) wrowA[i] = wt4[i];
#pragma unroll
    for (int i = 0; i < 16; i++) wrowB[i] = wt4[16 + i];
    const float bte = bt[e];

    zbuf[j][0][e] = latent[zi[b] * EMBED + e];
    __syncthreads();

    int cur = 0;
    for (int t = 0; t < TSTEPS; t++) {
        const float zc = zbuf[j][cur][e];
        zstash[j][t * EMBED + e] = f2bf_raw(zc * LOG2E);

        // half-dot A: k in [0,64) — op order identical to R11 (verified)
        const float4* z4 = reinterpret_cast<const float4*>(&zbuf[j][cur][0]);
        float4 accA = {0.f, 0.f, 0.f, 0.f};
#pragma unroll
        for (int i = 0; i < 16; i++) {
            float4 zv = z4[i];
            accA.x += zv.x * wrowA[i].x;
            accA.y += zv.y * wrowA[i].y;
            accA.z += zv.z * wrowA[i].z;
            accA.w += zv.w * wrowA[i].w;
        }
        float vA = accA.x + accA.y + accA.z + accA.w;
        // half-dot B: k in [64,128)
        float4 accB = {0.f, 0.f, 0.f, 0.f};
#pragma unroll
        for (int i = 0; i < 16; i++) {
            float4 zv = z4[16 + i];
            accB.x += zv.x * wrowB[i].x;
            accB.y += zv.y * wrowB[i].y;
            accB.z += zv.z * wrowB[i].z;
            accB.w += zv.w * wrowB[i].w;
        }
        float vB = accB.x + accB.y + accB.z + accB.w;

        float znew = fast_tanh_nr(((zc + vA) + vB) + bte);
        zbuf[j][cur ^ 1][e] = znew;
        __syncthreads();                    // lgkmcnt-only drain (no stores)
        cur ^= 1;
    }

    // bulk store this chain's 32 KB: bf16 copy (tail) + fp8 (gemm A)
    uint4* dstb = reinterpret_cast<uint4*>(zsb + (long)b * TSTEPS * EMBED);
    uint2* dsta = reinterpret_cast<uint2*>(zsa8 + (long)b * TSTEPS * EMBED);
    const uint4* src = reinterpret_cast<const uint4*>(&zstash[j][0]);
    for (int i = e; i < TSTEPS * EMBED / 8; i += 128) {
        uint4 w = src[i];                   // 8 bf16 (z * log2e)
        dstb[i] = w;
        float f0 = bf_raw2f(w.x & 0xffff), f1 = bf_raw2f(w.x >> 16);
        float f2 = bf_raw2f(w.y & 0xffff), f3 = bf_raw2f(w.y >> 16);
        float f4 = bf_raw2f(w.z & 0xffff), f5 = bf_raw2f(w.z >> 16);
        float f6 = bf_raw2f(w.w & 0xffff), f7 = bf_raw2f(w.w >> 16);
        int lo = pk_fp8<false>(f0, f1, 0); lo = pk_fp8<true>(f2, f3, lo);
        int hi = pk_fp8<false>(f4, f5, 0); hi = pk_fp8<true>(f6, f7, hi);
        uint2 o; o.x = (unsigned int)lo; o.y = (unsigned int)hi;
        dsta[i] = o;
    }
}

// ---------------------------------------------------------------------------
// K1: fused GEMM + sum-of-exp2, fp8 operands (R14-verified 63.5us).
// Round-15 change: GRIDX 64->128.  R14's occupancy was 29% with a 1024-block
// grid (4 blocks/CU) while the fp8 kernel's 18KB LDS + 60 VGPR allow 8
// blocks/CU — the grid was the limiter.  2048 blocks doubles resident waves
// hiding the per-group barrier drain.  (R10's GRIDX=128 bf16 regression was
// LDS-capped at 4 blocks/CU — no occupancy gain was possible there.)
// Structure: 4 waves x 64 rows = 256 rows x 6-7 groups of 64 N-cols,
// double-buffered 8KB LDS B-tiles via global_load_lds w=16 + XOR-8 granule
// swizzle, one barrier per group, LDS bias slice, zero-C init,
// sums = fma(exp2(d), exp2(bias), sums).
// fp8 A/B fragment (16x16x32): lane holds [m|n = lane&15][k = quad*8+j],
// j=0..7 packed LSB-first in one i64.  D: row=(lane>>4)*4+r, col=lane&15.
// ---------------------------------------------------------------------------
typedef __attribute__((ext_vector_type(4))) float f32x4;

__global__ __launch_bounds__(256) void gemm_lse_kernel(const unsigned char* __restrict__ zsa8,
                                                       const unsigned char* __restrict__ wv8,
                                                       const float* __restrict__ bvs,
                                                       float* __restrict__ S) {
    __shared__ unsigned char ldsb[2][8192];  // 2 x 8 KB fp8 B tiles
    __shared__ float ldsbias[MAXGRP * 64];   // this block's bias slice (1.8 KB)

    const int lane  = threadIdx.x & 63;
    const int wave  = threadIdx.x >> 6;
    const int col16 = lane & 15;
    const int quad  = lane >> 4;
    const int mbase = blockIdx.y * 256 + wave * 64;

    // group range for this x-block: 786 = 128*6 + 18
    const int x  = blockIdx.x;
    const int g0 = x * 6 + min(x, 18);
    const int g1 = g0 + 6 + (x < 18 ? 1 : 0);
    const int nbias = (g1 - g0) * 64;

    // prologue: stage this block's bias slice into LDS
    for (int i = threadIdx.x; i < nbias; i += 256)
        ldsbias[i] = bvs[g0 * 64 + i];

    // A fragments: 4 M-subtiles x 4 K-chunks, one i64 each (32 VGPRs)
    unsigned long long a[4][4];
#pragma unroll
    for (int s = 0; s < 4; s++)
#pragma unroll
        for (int c = 0; c < 4; c++)
            a[s][c] = *reinterpret_cast<const unsigned long long*>(
                zsa8 + (long)(mbase + s * 16 + col16) * EMBED + c * 32 + quad * 8);

    float sums[16];
#pragma unroll
    for (int i = 0; i < 16; i++) sums[i] = 0.f;

    // stage group g's 8 KB fp8 B-tile into ldsb[buf] (XOR-8 swizzle)
    auto stage = [&](int buf, int g) {
#pragma unroll
        for (int j = 0; j < 2; j++) {
            const int rr = (wave * 2 + j) * 8 + (lane >> 3);   // B-row 0..63
            const int G  = (lane & 7) ^ (rr & 7);              // logical granule
            const unsigned char* gp = wv8 + (long)(g * 64 + rr) * EMBED + G * 16;
            __builtin_amdgcn_global_load_lds(
                (const __attribute__((address_space(1))) void*)gp,
                (__attribute__((address_space(3))) void*)&ldsb[buf][(wave * 2 + j) * 1024],
                16, 0, 0);
        }
    };

    int cur = 0;
    stage(0, g0);

    const f32x4 dzero = {0.f, 0.f, 0.f, 0.f};

    for (int g = g0; g < g1; g++) {
        __syncthreads();                     // buf[cur] + bias staged; prev reads done
        if (g + 1 < g1) stage(cur ^ 1, g + 1);

        const float* biasg = &ldsbias[(g - g0) * 64];

#pragma unroll
        for (int c = 0; c < 4; c++) {
            // fragment reads: row r = c*16+col16; byte offset q_abs*8
            // (q_abs = kc*4+quad); phys = ((q_abs>>1)^(r&7))*16 + (q_abs&1)*8
            const unsigned char* rowp = &ldsb[cur][(c * 16 + col16) * 128];
            const int r7 = col16 & 7;
            unsigned long long bf[4];
#pragma unroll
            for (int kc = 0; kc < 4; kc++) {
                const int q_abs = kc * 4 + quad;
                bf[kc] = *reinterpret_cast<const unsigned long long*>(
                    rowp + (((q_abs >> 1) ^ r7) * 16) + ((q_abs & 1) * 8));
            }

            const float eb = fast_exp2(biasg[c * 16 + col16]);  // 0 for pad

            // kc-outer, s-inner: consecutive MFMAs are independent (4 chains)
            f32x4 d[4];
#pragma unroll
            for (int s = 0; s < 4; s++)
                d[s] = __builtin_amdgcn_mfma_f32_16x16x32_fp8_fp8(
                    (long long)a[s][0], (long long)bf[0], dzero, 0, 0, 0);
#pragma unroll
            for (int kc = 1; kc < 4; kc++)
#pragma unroll
                for (int s = 0; s < 4; s++)
                    d[s] = __builtin_amdgcn_mfma_f32_16x16x32_fp8_fp8(
                        (long long)a[s][kc], (long long)bf[kc], d[s], 0, 0, 0);

#pragma unroll
            for (int s = 0; s < 4; s++)
#pragma unroll
                for (int r = 0; r < 4; r++)
                    sums[s * 4 + r] = fmaf(fast_exp2(d[s][r]), eb, sums[s * 4 + r]);
        }
        cur ^= 1;
    }

    // reduce partial sums over the 16 columns, one atomic per row per block
#pragma unroll
    for (int s = 0; s < 4; s++) {
#pragma unroll
        for (int r = 0; r < 4; r++) {
            float v = sums[s * 4 + r];
            v += __shfl_xor(v, 1);
            v += __shfl_xor(v, 2);
            v += __shfl_xor(v, 4);
            v += __shfl_xor(v, 8);
            if (col16 == 0)
                atomicAdd(&S[mbase + s * 16 + quad * 4 + r], v);
        }
    }
}

// ---------------------------------------------------------------------------
// K2: yp[row] = ln2*(dot_scaled - log2(S[row])) + bv[y[row]], where
// dot_scaled = (bf16 zsb row) . (fp32 Wv[y] row)  -- zsb is z*log2e in bf16;
// bf16 quantization adds only ~1e-3 to the target dot.
// One wave per row; lane l handles elements {2l, 2l+1}.
// ---------------------------------------------------------------------------
__global__ __launch_bounds__(256) void tail_kernel(const unsigned short* __restrict__ zsb,
                                                   const float* __restrict__ Wv,
                                                   const float* __restrict__ bv,
                                                   const int* __restrict__ y,
                                                   const float* __restrict__ S,
                                                   float* __restrict__ out) {
    const int row  = blockIdx.x * 4 + (threadIdx.x >> 6);
    const int lane = threadIdx.x & 63;
    const int yv = y[row];
    const ushort2* zr = reinterpret_cast<const ushort2*>(zsb + (long)row * EMBED);
    const float2*  wr = reinterpret_cast<const float2*>(Wv + (long)yv * EMBED);
    ushort2 z2 = zr[lane];
    float2  w2 = wr[lane];
    float v = bf_raw2f(z2.x) * w2.x + bf_raw2f(z2.y) * w2.y;
    v += __shfl_xor(v, 32);
    v += __shfl_xor(v, 16);
    v += __shfl_xor(v, 8);
    v += __shfl_xor(v, 4);
    v += __shfl_xor(v, 2);
    v += __shfl_xor(v, 1);
    if (lane == 0)
        out[row] = LN2 * (v - fast_log2(S[row])) + bv[yv];
}

// ---------------------------------------------------------------------------
extern "C" void kernel_launch(void* const* d_in, const int* in_sizes, int n_in,
                              void* d_out, int out_size, void* d_ws, size_t ws_size,
                              hipStream_t stream) {
    const int*   zi     = (const int*)d_in[0];
    const int*   y      = (const int*)d_in[1];
    const float* latent = (const float*)d_in[2];
    const float* Wt     = (const float*)d_in[3];
    const float* bt     = (const float*)d_in[4];
    const float* Wv     = (const float*)d_in[5];
    const float* bv     = (const float*)d_in[6];
    float* out = (float*)d_out;

    char* ws = (char*)d_ws;
    // workspace layout (~8.3 MB total):
    unsigned short* zsb  = (unsigned short*)ws;                        // 1 MB   @ 0
    unsigned char*  zsa8 = (unsigned char*)(ws + (1u << 20));          // 0.5 MB @ 1M
    float*          S    = (float*)(ws + 1536u * 1024);                // 16 KB  @ 1.5M
    float*          bvs  = (float*)(ws + 1536u * 1024 + (64u << 10));  // 197 KB @ 1.5M+64K
    unsigned char*  wv8  = (unsigned char*)(ws + (2u << 20));          // 6.14MB @ 2M

    setup_kernel<<<SCANB + CONV_BLOCKS, 256, 0, stream>>>(zi, latent, Wt, bt, Wv, bv,
                                                          zsb, zsa8, wv8, bvs, S);

    gemm_lse_kernel<<<dim3(GRIDX, GRIDY), 256, 0, stream>>>(zsa8, wv8, bvs, S);

    tail_kernel<<<MROWS / 4, 256, 0, stream>>>(zsb, Wv, bv, y, S, out);
}